// Round 5
// baseline (150.778 us; speedup 1.0000x reference)
//
#include <hip/hip_runtime.h>
#include <hip/hip_fp16.h>
#include <hip/hip_cooperative_groups.h>
#include <math.h>

namespace cg = cooperative_groups;

typedef _Float16 f16x8 __attribute__((ext_vector_type(8)));
typedef float f32x4 __attribute__((ext_vector_type(4)));

#define NS 4
#define HID 512
#define IN_DIM 342
#define OUT_DIM 311
#define BATCH 1024
#define INP 352            // IN_DIM padded to mult of 32
#define K0V (NS*INP)       // 1408
#define K12V (NS*HID)      // 2048
#define XROW (IN_DIM+1)    // 343

// workspace float offsets (~11.9 MB total)
#define OFF_ACOEF 0
#define OFF_X0H   4096
#define OFF_W0H   (OFF_X0H + 720896)
#define OFF_W1H   (OFF_W0H + 360448)
#define OFF_W2H   (OFF_W1H + 524288)
#define OFF_H1X   (OFF_W2H + 327680)
#define OFF_H2X   OFF_X0H      // H2x (4MB) overlays X0h+part of W0h, both dead after L0

// ---------------- GEMM phase (device function) ----------------
// BM=32 x BN=64, BK=128. 8 waves: split-K groups g=0/1 (64 k each),
// within group: wm=(wid>>1)&1 (16-row half), wn=wid&1 (32-col half).
// LDS: sA 8KB | sB 16KB per buffer, double buffered (48KB).
// LAYER 0/1: outH[row*2048 + s*512 + col] = f16(c_s * ELU(v)); LAYER 2: outF.
template<int LAYER>
__device__ __forceinline__ void gemm_phase(
    const __half* __restrict__ A,
    const __half* __restrict__ Bw,
    const float* __restrict__ acoef,
    const float* __restrict__ bias,
    __half* __restrict__ outH,
    float* __restrict__ outF,
    char (*lbuf)[24576])
{
    constexpr int K  = (LAYER==0) ? K0V : K12V;
    constexpr int NB = (LAYER==2) ? OUT_DIM : HID;
    constexpr int NITER = K / 128;

    if (LAYER == 2 && blockIdx.x >= 160) return;   // 160 tiles for N=320

    const int tile = blockIdx.x;
    const int m0 = (tile & 31) * 32;
    const int n0 = (tile >> 5) * 64;

    const int t    = threadIdx.x;
    const int lane = t & 63;
    const int wid  = t >> 6;
    const int g    = wid >> 2;
    const int wm   = (wid >> 1) & 1;
    const int wn   = wid & 1;

    // staging: A 32x128 f16 (512 x 16B), B 64x128 f16 (512 x 32B)
    const __half* aSrc = A + (size_t)(m0 + (t>>4))*K + (t&15)*8;
    const int aRow = t>>4;
    const int aOff = aRow*256 + (((t&15)*16) ^ ((aRow&7)<<4));
    const __half* bSrc = Bw + (size_t)(n0 + (t>>3))*K + (t&7)*16;
    const int bRow = t>>3;
    const int bOff0 = 8192 + bRow*256 + ((((t&7)*2  )*16) ^ ((bRow&7)<<4));
    const int bOff1 = 8192 + bRow*256 + ((((t&7)*2+1)*16) ^ ((bRow&7)<<4));

    f32x4 acc[2] = {};

    uint4 va  = *(const uint4*)(aSrc);
    uint4 vb0 = *(const uint4*)(bSrc);
    uint4 vb1 = *(const uint4*)(bSrc + 8);
    *(uint4*)(lbuf[0] + aOff)  = va;
    *(uint4*)(lbuf[0] + bOff0) = vb0;
    *(uint4*)(lbuf[0] + bOff1) = vb1;

    for (int it = 0; it < NITER; ++it) {
        __syncthreads();
        if (it + 1 < NITER) {                 // prefetch next tile early
            va  = *(const uint4*)(aSrc + (it+1)*128);
            vb0 = *(const uint4*)(bSrc + (it+1)*128);
            vb1 = *(const uint4*)(bSrc + (it+1)*128 + 8);
        }
        const char* sA = lbuf[it & 1];
        const char* sB = lbuf[it & 1] + 8192;
        #pragma unroll
        for (int kk = 0; kk < 2; ++kk) {
            const int kb = g*128 + kk*64 + (lane>>4)*16;   // byte off in 256B row
            const int rr = wm*16 + (lane&15);
            f16x8 af = *(const f16x8*)(sA + rr*256 + (kb ^ ((rr&7)<<4)));
            #pragma unroll
            for (int ni = 0; ni < 2; ++ni) {
                const int oo = wn*32 + ni*16 + (lane&15);
                f16x8 bf = *(const f16x8*)(sB + oo*256 + (kb ^ ((oo&7)<<4)));
                acc[ni] = __builtin_amdgcn_mfma_f32_16x16x32_f16(af, bf, acc[ni], 0, 0, 0);
            }
        }
        if (it + 1 < NITER) {
            char* d = lbuf[(it+1) & 1];
            *(uint4*)(d + aOff)  = va;
            *(uint4*)(d + bOff0) = vb0;
            *(uint4*)(d + bOff1) = vb1;
        }
    }

    // ---- split-K reduction: g1 stores partials, g0 adds ----
    __syncthreads();
    float* red = (float*)lbuf[0];             // 32x64 f32 = 8KB
    if (g == 1) {
        #pragma unroll
        for (int ni = 0; ni < 2; ++ni)
            #pragma unroll
            for (int r = 0; r < 4; ++r) {
                int rl = wm*16 + (lane>>4)*4 + r;
                int cl = wn*32 + ni*16 + (lane&15);
                red[rl*64 + cl] = acc[ni][r];
            }
    }
    __syncthreads();
    if (g != 0) return;

    #pragma unroll
    for (int ni = 0; ni < 2; ++ni)
        #pragma unroll
        for (int r = 0; r < 4; ++r) {
            int rl = wm*16 + (lane>>4)*4 + r;
            int cl = wn*32 + ni*16 + (lane&15);
            acc[ni][r] += red[rl*64 + cl];
        }

    // epilogue: D layout col=lane&15, row=(lane>>4)*4+r
    #pragma unroll
    for (int r = 0; r < 4; ++r) {
        const int row = m0 + wm*16 + (lane>>4)*4 + r;
        const float c0 = acoef[row*4+0], c1 = acoef[row*4+1],
                    c2 = acoef[row*4+2], c3 = acoef[row*4+3];
        #pragma unroll
        for (int ni = 0; ni < 2; ++ni) {
            const int col = n0 + wn*32 + ni*16 + (lane&15);
            float v = acc[ni][r];
            if (LAYER == 2) {
                if (col < OUT_DIM) {
                    float bi = c0*bias[col] + c1*bias[NB+col]
                             + c2*bias[2*NB+col] + c3*bias[3*NB+col];
                    outF[(size_t)row*OUT_DIM + col] = v + bi;
                }
            } else {
                float bi = c0*bias[col] + c1*bias[NB+col]
                         + c2*bias[2*NB+col] + c3*bias[3*NB+col];
                v += bi;
                v = (v > 0.f) ? v : expm1f(v);
                size_t o = (size_t)row*K12V + col;
                outH[o        ] = __float2half(c0*v);
                outH[o +   HID] = __float2half(c1*v);
                outH[o + 2*HID] = __float2half(c2*v);
                outH[o + 3*HID] = __float2half(c3*v);
            }
        }
    }
}

// ---------------- fused cooperative kernel ----------------
// phase 0: prep (1952 jobs: 512 W0 rows, 256 W1 2-row jobs, 160 W2 2-row
//          jobs, 1024 X0 rows) -> grid.sync -> L0 -> sync -> L1 -> sync -> L2
__global__ __launch_bounds__(512, 1) void fused(
    const float* __restrict__ x,
    const float* __restrict__ W0, const float* __restrict__ W1,
    const float* __restrict__ W2,
    const float* __restrict__ b0, const float* __restrict__ b1,
    const float* __restrict__ b2,
    float* __restrict__ acoef,
    __half* __restrict__ X0h, __half* __restrict__ W0h,
    __half* __restrict__ W1h, __half* __restrict__ W2h,
    __half* __restrict__ H1x, __half* __restrict__ H2x,
    float* __restrict__ out)
{
    __shared__ __align__(16) char lbuf[2][24576];
    cg::grid_group grid = cg::this_grid();
    const int t = threadIdx.x;

    for (int job = blockIdx.x; job < 1952; job += gridDim.x) {
        if (job < 512) {                       // W0h row (padded K=1408)
            int o = job;
            for (int k = t; k < K0V; k += 512) {
                int s = k / INP;
                int i = k - s*INP;
                float v = (i < IN_DIM) ? W0[((size_t)s*HID + o)*IN_DIM + i] : 0.f;
                W0h[(size_t)o*K0V + k] = __float2half(v);
            }
        } else if (job < 768) {                // W1h, 2 rows per job
            int o = (job - 512)*2 + (t >> 8);
            int k = (t & 255) * 8;
            int s = k >> 9, i = k & 511;
            const float* src = W1 + ((size_t)s*HID + o)*HID + i;
            float4 v0 = *(const float4*)(src);
            float4 v1 = *(const float4*)(src + 4);
            f16x8 h;
            h[0]=(_Float16)v0.x; h[1]=(_Float16)v0.y; h[2]=(_Float16)v0.z; h[3]=(_Float16)v0.w;
            h[4]=(_Float16)v1.x; h[5]=(_Float16)v1.y; h[6]=(_Float16)v1.z; h[7]=(_Float16)v1.w;
            *(f16x8*)(W1h + (size_t)o*K12V + k) = h;
        } else if (job < 928) {                // W2h, 2 rows per job
            int o = (job - 768)*2 + (t >> 8);  // 0..319
            int k = (t & 255) * 8;
            int s = k >> 9, i = k & 511;
            f16x8 h = {};
            if (o < OUT_DIM) {
                const float* src = W2 + ((size_t)s*OUT_DIM + o)*HID + i;
                float4 v0 = *(const float4*)(src);
                float4 v1 = *(const float4*)(src + 4);
                h[0]=(_Float16)v0.x; h[1]=(_Float16)v0.y; h[2]=(_Float16)v0.z; h[3]=(_Float16)v0.w;
                h[4]=(_Float16)v1.x; h[5]=(_Float16)v1.y; h[6]=(_Float16)v1.z; h[7]=(_Float16)v1.w;
            }
            *(f16x8*)(W2h + (size_t)o*K12V + k) = h;
        } else {                               // X0h row b + acoef
            int b = job - 928;
            float phase = x[(size_t)b*XROW + IN_DIM];
            float ps = (float)NS * phase;
            float mu = ps - floorf(ps);
            int i1 = ((int)ps) & (NS-1);
            float mu2 = mu*mu, mu3 = mu2*mu;
            float c1 =  1.5f*mu3 - 2.5f*mu2 + 1.0f;        // rel 0
            float c2 = -1.5f*mu3 + 2.0f*mu2 + 0.5f*mu;     // rel 1
            float c3 =  0.5f*mu3 - 0.5f*mu2;               // rel 2
            float c0 = -0.5f*mu3 +      mu2 - 0.5f*mu;     // rel 3
            if (t < 4) {
                int rel = (t - i1) & 3;
                acoef[b*4 + t] = (rel==0)?c1:(rel==1)?c2:(rel==2)?c3:c0;
            }
            for (int k = t; k < K0V; k += 512) {
                int s = k / INP;
                int i = k - s*INP;
                int rel = (s - i1) & 3;
                float sel = (rel==0)?c1:(rel==1)?c2:(rel==2)?c3:c0;
                float v = (i < IN_DIM) ? x[(size_t)b*XROW + i] * sel : 0.f;
                X0h[(size_t)b*K0V + k] = __float2half(v);
            }
        }
    }

    grid.sync();
    gemm_phase<0>(X0h, W0h, acoef, b0, H1x, nullptr, lbuf);
    grid.sync();
    gemm_phase<1>(H1x, W1h, acoef, b1, H2x, nullptr, lbuf);
    grid.sync();
    gemm_phase<2>(H2x, W2h, acoef, b2, nullptr, out, lbuf);
}

extern "C" void kernel_launch(void* const* d_in, const int* in_sizes, int n_in,
                              void* d_out, int out_size, void* d_ws, size_t ws_size,
                              hipStream_t stream) {
    const float* x  = (const float*)d_in[0];
    const float* W0 = (const float*)d_in[1];
    const float* W1 = (const float*)d_in[2];
    const float* W2 = (const float*)d_in[3];
    const float* b0 = (const float*)d_in[4];
    const float* b1 = (const float*)d_in[5];
    const float* b2 = (const float*)d_in[6];
    float* out = (float*)d_out;
    float* ws  = (float*)d_ws;

    float*  acoef = ws + OFF_ACOEF;
    __half* X0h   = (__half*)(ws + OFF_X0H);
    __half* W0h   = (__half*)(ws + OFF_W0H);
    __half* W1h   = (__half*)(ws + OFF_W1H);
    __half* W2h   = (__half*)(ws + OFF_W2H);
    __half* H1x   = (__half*)(ws + OFF_H1X);
    __half* H2x   = (__half*)(ws + OFF_H2X);

    void* args[] = { (void*)&x, (void*)&W0, (void*)&W1, (void*)&W2,
                     (void*)&b0, (void*)&b1, (void*)&b2,
                     (void*)&acoef, (void*)&X0h, (void*)&W0h, (void*)&W1h,
                     (void*)&W2h, (void*)&H1x, (void*)&H2x, (void*)&out };
    hipLaunchCooperativeKernel((const void*)fused, dim3(256), dim3(512),
                               args, 0, stream);
}

// Round 6
// 72.622 us; speedup vs baseline: 2.0762x; 2.0762x over previous
//
#include <hip/hip_runtime.h>
#include <hip/hip_fp16.h>
#include <math.h>

typedef _Float16 f16x8 __attribute__((ext_vector_type(8)));
typedef float f32x4 __attribute__((ext_vector_type(4)));

#define NS 4
#define HID 512
#define IN_DIM 342
#define OUT_DIM 311
#define BATCH 1024
#define INP 352            // IN_DIM padded to mult of 32 (virtual)
#define K0V (NS*INP)       // 1408
#define K12V (NS*HID)      // 2048
#define XROW (IN_DIM+1)    // 343

// workspace float offsets: only the two prescaled activations now
#define OFF_H1X 0                     // 1024*2048 f16 = 1048576 fl (4MB)
#define OFF_H2X (OFF_H1X + 1048576)   // 4MB

// Catmull-Rom basis per slice s given phase
__device__ __forceinline__ void coefs4(float phase, float* c) {
    float ps = (float)NS * phase;
    float mu = ps - floorf(ps);
    int i1 = ((int)ps) & 3;
    float mu2 = mu*mu, mu3 = mu2*mu;
    float r0 =  1.5f*mu3 - 2.5f*mu2 + 1.0f;        // rel 0 (s==i1)
    float r1 = -1.5f*mu3 + 2.0f*mu2 + 0.5f*mu;     // rel 1
    float r2 =  0.5f*mu3 - 0.5f*mu2;               // rel 2
    float r3 = -0.5f*mu3 +      mu2 - 0.5f*mu;     // rel 3
    #pragma unroll
    for (int s = 0; s < 4; ++s) {
        int rel = (s - i1) & 3;
        c[s] = (rel==0)?r0:(rel==1)?r1:(rel==2)?r2:r3;
    }
}

// ---- fused GEMM: C[row][col] = sum_k A'[row][k]*B'[col][k] + bias interp ----
// BM=32 x BN=64, BK=128; 8 waves: split-K g=0/1, wm=(wid>>1)&1, wn=wid&1.
// A': L0 = f16(c_s * x[row][i]) staged from f32 x; L1/2 = prescaled f16 Ah.
// B': f16(W[s][col][i]) staged from ORIGINAL f32 weights (no prep pass).
// LDS double buffer, 1 barrier/iter, XOR-swizzled (both sides).
template<int LAYER>
__global__ __launch_bounds__(512) void gemm_fused(
    const float* __restrict__ x,
    const float* __restrict__ Wsrc,
    const __half* __restrict__ Ah,
    const float* __restrict__ bias,
    __half* __restrict__ outH,
    float* __restrict__ outF)
{
    constexpr int K  = (LAYER==0) ? K0V : K12V;
    constexpr int NB = (LAYER==2) ? OUT_DIM : HID;   // bias/W row-count stride
    constexpr int NITER = K / 128;

    __shared__ __align__(16) char lbuf[2][24576];    // sA 8KB | sB 16KB each

    const int tile = blockIdx.x;
    const int m0 = (tile & 31) * 32;
    const int n0 = (tile >> 5) * 64;

    const int t    = threadIdx.x;
    const int lane = t & 63;
    const int wid  = t >> 6;
    const int g    = wid >> 2;
    const int wm   = (wid >> 1) & 1;
    const int wn   = wid & 1;

    // A staging: thread -> row t>>4 (0..31), 8-k chunk t&15
    const int aRow = t >> 4;
    const int aC   = t & 15;
    const int aOff = aRow*256 + ((aC*16) ^ ((aRow&7)<<4));
    float myc[4];
    if (LAYER == 0) coefs4(x[(size_t)(m0+aRow)*XROW + IN_DIM], myc);
    const __half* aSrcH = Ah + (size_t)(m0 + aRow)*K + aC*8;

    // B staging: thread -> row t>>3 (0..63), 16-k chunk t&7
    const int bRow = t >> 3;
    const int bC   = t & 7;
    const int bOff0 = 8192 + bRow*256 + (((bC*2  )*16) ^ ((bRow&7)<<4));
    const int bOff1 = 8192 + bRow*256 + (((bC*2+1)*16) ^ ((bRow&7)<<4));
    const int bO = n0 + bRow;

    auto stageA = [&](int k0, char* dst) {
        f16x8 h;
        if (LAYER == 0) {
            int k = k0 + aC*8;             // 352%8==0: chunk never crosses slice
            int s = k / INP;
            int i = k - s*INP;
            const float* src = x + (size_t)(m0+aRow)*XROW + i;
            float sc = myc[s];
            if (i + 8 <= IN_DIM) {
                #pragma unroll
                for (int j=0;j<8;++j) h[j] = (_Float16)(src[j]*sc);
            } else {
                #pragma unroll
                for (int j=0;j<8;++j) h[j] = (_Float16)((i+j < IN_DIM) ? src[j]*sc : 0.f);
            }
        } else {
            h = *(const f16x8*)(aSrcH + k0);
        }
        *(f16x8*)(dst + aOff) = h;
    };

    auto stageB = [&](int k0, char* dst) {
        f16x8 h0 = {}, h1 = {};
        int k = k0 + bC*16;                // 352%16==0 and 512%16==0: no crossing
        if (LAYER == 0) {
            int s = k / INP;
            int i = k - s*INP;
            const float* src = Wsrc + ((size_t)s*HID + bO)*IN_DIM + i;
            if (i + 16 <= IN_DIM) {
                #pragma unroll
                for (int j=0;j<8;++j) h0[j] = (_Float16)src[j];
                #pragma unroll
                for (int j=0;j<8;++j) h1[j] = (_Float16)src[8+j];
            } else {
                #pragma unroll
                for (int j=0;j<8;++j) h0[j] = (_Float16)((i+j   < IN_DIM) ? src[j]   : 0.f);
                #pragma unroll
                for (int j=0;j<8;++j) h1[j] = (_Float16)((i+8+j < IN_DIM) ? src[8+j] : 0.f);
            }
        } else {
            int s = k >> 9, i = k & 511;
            if (LAYER != 2 || bO < OUT_DIM) {
                const float* src = Wsrc + ((size_t)s*NB + bO)*HID + i;
                float4 v0 = *(const float4*)(src);
                float4 v1 = *(const float4*)(src+4);
                float4 v2 = *(const float4*)(src+8);
                float4 v3 = *(const float4*)(src+12);
                h0[0]=(_Float16)v0.x; h0[1]=(_Float16)v0.y; h0[2]=(_Float16)v0.z; h0[3]=(_Float16)v0.w;
                h0[4]=(_Float16)v1.x; h0[5]=(_Float16)v1.y; h0[6]=(_Float16)v1.z; h0[7]=(_Float16)v1.w;
                h1[0]=(_Float16)v2.x; h1[1]=(_Float16)v2.y; h1[2]=(_Float16)v2.z; h1[3]=(_Float16)v2.w;
                h1[4]=(_Float16)v3.x; h1[5]=(_Float16)v3.y; h1[6]=(_Float16)v3.z; h1[7]=(_Float16)v3.w;
            }
        }
        *(f16x8*)(dst + bOff0) = h0;
        *(f16x8*)(dst + bOff1) = h1;
    };

    f32x4 acc[2] = {};

    stageA(0, lbuf[0]);
    stageB(0, lbuf[0]);

    for (int it = 0; it < NITER; ++it) {
        __syncthreads();
        if (it + 1 < NITER) {              // stage next tile (loads hoist early)
            stageA((it+1)*128, lbuf[(it+1)&1]);
            stageB((it+1)*128, lbuf[(it+1)&1]);
        }
        const char* sA = lbuf[it & 1];
        const char* sB = lbuf[it & 1] + 8192;
        #pragma unroll
        for (int kk = 0; kk < 2; ++kk) {
            const int kb = g*128 + kk*64 + (lane>>4)*16;
            const int rr = wm*16 + (lane&15);
            f16x8 af = *(const f16x8*)(sA + rr*256 + (kb ^ ((rr&7)<<4)));
            #pragma unroll
            for (int ni = 0; ni < 2; ++ni) {
                const int oo = wn*32 + ni*16 + (lane&15);
                f16x8 bf = *(const f16x8*)(sB + oo*256 + (kb ^ ((oo&7)<<4)));
                acc[ni] = __builtin_amdgcn_mfma_f32_16x16x32_f16(af, bf, acc[ni], 0, 0, 0);
            }
        }
    }

    // ---- split-K reduction ----
    __syncthreads();
    float* red = (float*)lbuf[0];
    if (g == 1) {
        #pragma unroll
        for (int ni = 0; ni < 2; ++ni)
            #pragma unroll
            for (int r = 0; r < 4; ++r) {
                int rl = wm*16 + (lane>>4)*4 + r;
                int cl = wn*32 + ni*16 + (lane&15);
                red[rl*64 + cl] = acc[ni][r];
            }
    }
    __syncthreads();
    if (g != 0) return;
    #pragma unroll
    for (int ni = 0; ni < 2; ++ni)
        #pragma unroll
        for (int r = 0; r < 4; ++r) {
            int rl = wm*16 + (lane>>4)*4 + r;
            int cl = wn*32 + ni*16 + (lane&15);
            acc[ni][r] += red[rl*64 + cl];
        }

    // ---- epilogue: recompute coefs per row, bias interp (+ELU), store ----
    #pragma unroll
    for (int r = 0; r < 4; ++r) {
        const int row = m0 + wm*16 + (lane>>4)*4 + r;
        float c[4];
        coefs4(x[(size_t)row*XROW + IN_DIM], c);
        #pragma unroll
        for (int ni = 0; ni < 2; ++ni) {
            const int col = n0 + wn*32 + ni*16 + (lane&15);
            float v = acc[ni][r];
            if (LAYER == 2) {
                if (col < OUT_DIM) {
                    float bi = c[0]*bias[col] + c[1]*bias[NB+col]
                             + c[2]*bias[2*NB+col] + c[3]*bias[3*NB+col];
                    outF[(size_t)row*OUT_DIM + col] = v + bi;
                }
            } else {
                float bi = c[0]*bias[col] + c[1]*bias[NB+col]
                         + c[2]*bias[2*NB+col] + c[3]*bias[3*NB+col];
                v += bi;
                v = (v > 0.f) ? v : expm1f(v);
                size_t o = (size_t)row*K12V + col;
                outH[o        ] = __float2half(c[0]*v);
                outH[o +   HID] = __float2half(c[1]*v);
                outH[o + 2*HID] = __float2half(c[2]*v);
                outH[o + 3*HID] = __float2half(c[3]*v);
            }
        }
    }
}

extern "C" void kernel_launch(void* const* d_in, const int* in_sizes, int n_in,
                              void* d_out, int out_size, void* d_ws, size_t ws_size,
                              hipStream_t stream) {
    const float* x  = (const float*)d_in[0];
    const float* W0 = (const float*)d_in[1];
    const float* W1 = (const float*)d_in[2];
    const float* W2 = (const float*)d_in[3];
    const float* b0 = (const float*)d_in[4];
    const float* b1 = (const float*)d_in[5];
    const float* b2 = (const float*)d_in[6];
    float* out = (float*)d_out;
    float* ws  = (float*)d_ws;

    __half* H1x = (__half*)(ws + OFF_H1X);
    __half* H2x = (__half*)(ws + OFF_H2X);

    gemm_fused<0><<<dim3(256), dim3(512), 0, stream>>>(x, W0, nullptr, b0, H1x, nullptr);
    gemm_fused<1><<<dim3(256), dim3(512), 0, stream>>>(x, W1, H1x,     b1, H2x, nullptr);
    gemm_fused<2><<<dim3(160), dim3(512), 0, stream>>>(x, W2, H2x,     b2, nullptr, out);
}